// Round 20
// baseline (90.267 us; speedup 1.0000x reference)
//
#include <hip/hip_runtime.h>
#include <hip/hip_bf16.h>

#define RTOT 49152
#define RT9  442368               // (RTOT/8) * 72, V-interleaved per-head stride
#define EPSF 1e-5f
#define SCQ 0.5101062398836783f   // (1/sqrt(8)) * log2(e)

typedef _Float16 h2 __attribute__((ext_vector_type(2)));
typedef _Float16 half8 __attribute__((ext_vector_type(8)));
typedef float f32x16 __attribute__((ext_vector_type(16)));

__device__ __forceinline__ h2 cvt2h(float a, float b) {
    return __builtin_bit_cast(h2, __builtin_amdgcn_cvt_pkrtz(a, b));
}
__device__ __forceinline__ unsigned int bcu(h2 v) { return __builtin_bit_cast(unsigned int, v); }

__device__ __forceinline__ void swap32(unsigned int& x, unsigned int& y, int hi) {
#if __has_builtin(__builtin_amdgcn_permlane32_swap)
    auto r = __builtin_amdgcn_permlane32_swap(x, y, false, false);
    x = r[0]; y = r[1];
#else
    unsigned int xs = (unsigned int)__shfl_xor((int)x, 32, 64);
    unsigned int ys = (unsigned int)__shfl_xor((int)y, 32, 64);
    unsigned int nx = hi ? ys : x;
    unsigned int ny = hi ? y : xs;
    x = nx; y = ny;
#endif
}

__device__ __forceinline__ half8 ldaf(const float* __restrict__ X, size_t base) {
    const float4* p = (const float4*)(X + base);
    float4 x = p[0], y = p[1];
    uint4 u = make_uint4(bcu(cvt2h(x.x, x.y)), bcu(cvt2h(x.z, x.w)),
                         bcu(cvt2h(y.x, y.y)), bcu(cvt2h(y.z, y.w)));
    return __builtin_bit_cast(half8, u);
}
__device__ __forceinline__ half8 ldbf(const char* WT, int e, int k0) {
    int off = ((e * 64 + k0) * 2) ^ ((e & 7) << 4);
    return *(const half8*)(WT + off);
}

// ---------------------------------------------------------------------------
// QKV projection (R19-proven): grid (192,3) x 512 thr, non-atomic stats
// partials sp1, block (0,0) zeroes stats_o. LDS-transpose coalesced stores.
// ---------------------------------------------------------------------------
__global__ __launch_bounds__(512) void gemm_qkv(
        const float* __restrict__ Qin, const float* __restrict__ Kin,
        const float* __restrict__ mask,
        const float* __restrict__ Wq, const float* __restrict__ bq,
        const float* __restrict__ Wk, const float* __restrict__ bk,
        const float* __restrict__ Wv, const float* __restrict__ bv,
        _Float16* __restrict__ Yq, _Float16* __restrict__ Yk,
        _Float16* __restrict__ Vr, _Float16* __restrict__ zt,
        float* __restrict__ sp1, float* __restrict__ stats_o) {
    __shared__ char WT[8192];
    __shared__ _Float16 YT[256 * 72];
    __shared__ float red[128];
    int tid = threadIdx.x;
    int which = blockIdx.y;
    const float* X    = which ? Kin : Qin;
    const float* W    = which == 0 ? Wq : (which == 1 ? Wk : Wv);
    const float* bias = which == 0 ? bq : (which == 1 ? bk : bv);

#pragma unroll
    for (int j = 0; j < 8; j++) {
        int i = j * 512 + tid;
        int d = i >> 6, e = i & 63;
        int off = ((e * 64 + d) * 2) ^ ((e & 7) << 4);
        *(_Float16*)(&WT[off]) = (_Float16)W[i];
    }
    if (tid < 128) red[tid] = 0.f;
    if (blockIdx.x == 0 && which == 0 && tid < 128)
        stats_o[tid] = 0.f;

    int wvi = tid >> 6, lane = tid & 63, ln = lane & 31, hi = lane >> 5;
    int row = blockIdx.x * 256 + wvi * 32 + ln;

    half8 af[4];
#pragma unroll
    for (int kc = 0; kc < 4; kc++)
        af[kc] = ldaf(X, (size_t)row * 64 + kc * 16 + 8 * hi);

    if ((int)(blockIdx.x % 3) == which && tid < 256) {
        int mrow = blockIdx.x * 256 + tid;
        const float4* mr = (const float4*)(mask + (size_t)mrow * 64);
        float s[8];
#pragma unroll
        for (int h8 = 0; h8 < 8; h8++) s[h8] = 0.f;
#pragma unroll
        for (int i = 0; i < 16; i++) {
            float4 m = mr[i];
            s[i >> 1] += m.x + m.y + m.z + m.w;
        }
#pragma unroll
        for (int h8 = 0; h8 < 8; h8++)
            zt[(size_t)h8 * RTOT + mrow] = (_Float16)((s[h8] == 0.f) ? 0.f : SCQ);
    }
    __syncthreads();

    f32x16 acc[2];
#pragma unroll
    for (int ct = 0; ct < 2; ct++) {
#pragma unroll
        for (int r = 0; r < 16; r++) acc[ct][r] = 0.f;
        int e = ct * 32 + ln;
#pragma unroll
        for (int kc = 0; kc < 4; kc++) {
            half8 bf = ldbf(WT, e, kc * 16 + 8 * hi);
            acc[ct] = __builtin_amdgcn_mfma_f32_32x32x16_f16(af[kc], bf, acc[ct], 0, 0, 0);
        }
    }

#pragma unroll
    for (int ct = 0; ct < 2; ct++) {
        int cc = ct * 32 + ln;
        float bv_ = bias[cc];
        float s = 0.f, q = 0.f;
#pragma unroll
        for (int r = 0; r < 16; r++) {
            float v = acc[ct][r] + bv_;
            s += v; q += v * v;
            int lrow = wvi * 32 + (r & 3) + 8 * (r >> 2) + 4 * hi;
            YT[lrow * 72 + cc] = (_Float16)v;
        }
        s += __shfl_xor(s, 32, 64);
        q += __shfl_xor(q, 32, 64);
        if (lane < 32) {
            atomicAdd(&red[cc], s);
            atomicAdd(&red[64 + cc], q);
        }
    }
    __syncthreads();
    if (tid < 128)
        sp1[((size_t)which * 192 + blockIdx.x) * 128 + tid] = red[tid];

    if (which < 2) {
        _Float16* Y = which == 0 ? Yq : Yk;
#pragma unroll
        for (int j = 0; j < 4; j++) {
            int idx = j * 512 + tid;
            int h = idx >> 8, r = idx & 255;
            half8 v = *(const half8*)&YT[r * 72 + h * 8];
            *(half8*)(Y + ((size_t)h * RTOT + blockIdx.x * 256 + r) * 8) = v;
        }
    } else {
        int chBase = blockIdx.x * 32;
#pragma unroll
        for (int j = 0; j < 4; j++) {
            int idx = j * 512 + tid;
            int h = idx >> 8, rem = idx & 255;
            int ch = rem >> 3, c = rem & 7;
            half8 w;
#pragma unroll
            for (int i = 0; i < 8; i++)
                w[i] = YT[(ch * 8 + i) * 72 + h * 8 + c];
            *(half8*)(Vr + (size_t)h * RT9 + (size_t)(chBase + ch) * 72 + c * 8) = w;
        }
        if (tid < 256) {
            int h = tid >> 5, ch = tid & 31;
            half8 one8;
#pragma unroll
            for (int i = 0; i < 8; i++) one8[i] = (_Float16)1.0f;
            *(half8*)(Vr + (size_t)h * RT9 + (size_t)(chBase + ch) * 72 + 64) = one8;
        }
    }
}

// ---------------------------------------------------------------------------
// MFMA attention, 1536 blocks x 256 thr (4 waves): p = bid mod 768,
// half = bid/768 (same-XCD pairing for L2 reuse of duplicated K/V staging).
// Wave wv handles strips half*8+wv and half*8+wv+4, fused in one t-loop
// (R18 core). Stats from sp1 partials (48 vals x 4 parts x 48 blocks).
// ---------------------------------------------------------------------------
__global__ __launch_bounds__(256) void attn_mfma(
        const _Float16* __restrict__ Yq, const _Float16* __restrict__ Yk,
        const _Float16* __restrict__ Vr, const _Float16* __restrict__ zt,
        const float* __restrict__ sp1,
        const float* __restrict__ gq, const float* __restrict__ betaq,
        const float* __restrict__ gk, const float* __restrict__ betak,
        const float* __restrict__ gv, const float* __restrict__ betav,
        _Float16* __restrict__ O) {
    __shared__ __align__(16) _Float16 KL[4096];   // 8 KB [m][8]
    __shared__ __align__(16) _Float16 VS[4608];   // 9 KB [m/8][9][8]
    __shared__ __align__(16) _Float16 OL[2048];   // 4 KB: this half's 256 rows
    __shared__ float SR[48];
    __shared__ float CF2[48];

    int bid = blockIdx.x;
    int p = (bid < 768) ? bid : bid - 768;
    int half_ = (bid < 768) ? 0 : 1;
    int h = p / 96;
    int bt = p - h * 96;
    int row0 = bt * 512;
    int co = h * 8;
    int tid = threadIdx.x;

    int wv = tid >> 6;           // 0..3
    int lane = tid & 63;
    int ln = lane & 31;
    int hi = lane >> 5;

    const _Float16* Ykh = Yk + ((size_t)h * RTOT + row0) * 8;
    const _Float16* Vrh = Vr + (size_t)h * RT9 + (size_t)(row0 >> 3) * 72;
    const _Float16* Yqh = Yq + ((size_t)h * RTOT + row0) * 8;

    // prefetch Q rows + mask factors for this wave's two strips
    half8 yqs[2];
    float zms[2];
    if (!hi) {
#pragma unroll
        for (int s = 0; s < 2; s++) {
            int n0 = (half_ * 8 + wv + 4 * s) * 32;
            yqs[s] = *(const half8*)(Yqh + (n0 + ln) * 8);
            zms[s] = (float)zt[(size_t)h * RTOT + row0 + n0 + ln];
        }
    }
    // prefetch K rows (2/thread) and V chunks (2-3/thread)
    half8 yk0 = *(const half8*)(Ykh + tid * 8);
    half8 yk1 = *(const half8*)(Ykh + (256 + tid) * 8);
    half8 vv0 = ((const half8*)Vrh)[tid];
    half8 vv1 = ((const half8*)Vrh)[256 + tid];
    half8 vv2;
    if (tid < 64) vv2 = ((const half8*)Vrh)[512 + tid];

    // stats: 48 values x 4 parts x 48 blocks (192 threads), overlaps prefetch
    if (tid < 192) {
        int v = tid >> 2, part = tid & 3;
        int s = v >> 4, i16 = v & 15;
        int ci = (i16 < 8) ? (co + i16) : (64 + co + (i16 - 8));
        const float* base = sp1 + ((size_t)s * 192 + part * 48) * 128 + ci;
        float a = 0.f;
#pragma unroll
        for (int b = 0; b < 48; b++)
            a += base[b * 128];
        a += __shfl_xor(a, 1, 64);
        a += __shfl_xor(a, 2, 64);
        if (part == 0) SR[v] = a;
    }
    __syncthreads();
    if (tid < 24) {
        int s = tid >> 3, c7 = tid & 7;
        const float* g  = s == 0 ? gq : (s == 1 ? gk : gv);
        const float* be = s == 0 ? betaq : (s == 1 ? betak : betav);
        float inv = 1.f / (float)RTOT;
        float mean = SR[s * 16 + c7] * inv;
        float var  = SR[s * 16 + 8 + c7] * inv - mean * mean;
        float a = g[co + c7] * rsqrtf(var + EPSF);
        CF2[s * 16 + c7] = a;
        CF2[s * 16 + 8 + c7] = be[co + c7] - mean * a;
    }
    __syncthreads();   // CF2 ready

    // K staging (2 rows/thread)
    {
        half8 kv0, kv1;
#pragma unroll
        for (int c = 0; c < 8; c++) {
            float a = CF2[16 + c], b = CF2[24 + c];
            kv0[c] = (_Float16)fmaxf(a * (float)yk0[c] + b, 0.f);
            kv1[c] = (_Float16)fmaxf(a * (float)yk1[c] + b, 0.f);
        }
        *(half8*)&KL[tid * 8] = kv0;
        *(half8*)&KL[(256 + tid) * 8] = kv1;
    }
    // V staging
    {
        int c0 = tid % 9;
        if (c0 < 8) {
            float a = CF2[32 + c0], b = CF2[40 + c0];
#pragma unroll
            for (int e = 0; e < 8; e++)
                vv0[e] = (_Float16)fmaxf(a * (float)vv0[e] + b, 0.f);
        }
        ((half8*)VS)[tid] = vv0;
        int c1 = (256 + tid) % 9;
        if (c1 < 8) {
            float a = CF2[32 + c1], b = CF2[40 + c1];
#pragma unroll
            for (int e = 0; e < 8; e++)
                vv1[e] = (_Float16)fmaxf(a * (float)vv1[e] + b, 0.f);
        }
        ((half8*)VS)[256 + tid] = vv1;
        if (tid < 64) {
            int c2 = (512 + tid) % 9;
            if (c2 < 8) {
                float a = CF2[32 + c2], b = CF2[40 + c2];
#pragma unroll
                for (int e = 0; e < 8; e++)
                    vv2[e] = (_Float16)fmaxf(a * (float)vv2[e] + b, 0.f);
            }
            ((half8*)VS)[512 + tid] = vv2;
        }
    }
    __syncthreads();

    f32x16 m12;
#pragma unroll
    for (int r = 0; r < 16; r++) m12[r] = -12.f;
    half8 hzero;
#pragma unroll
    for (int i = 0; i < 8; i++) hzero[i] = (_Float16)0.f;

    half8 qf0 = hzero, qf1 = hzero;
    if (!hi) {
#pragma unroll
        for (int c = 0; c < 8; c++) {
            qf0[c] = (_Float16)(fmaxf(CF2[c] * (float)yqs[0][c] + CF2[8 + c], 0.f) * zms[0]);
            qf1[c] = (_Float16)(fmaxf(CF2[c] * (float)yqs[1][c] + CF2[8 + c], 0.f) * zms[1]);
        }
    }

    f32x16 acc0, acc1;
#pragma unroll
    for (int r = 0; r < 16; r++) { acc0[r] = 0.f; acc1[r] = 0.f; }

#pragma unroll 2
    for (int t = 0; t < 16; t++) {
        half8 kf = hzero;
        if (!hi) kf = *(const half8*)&KL[(t * 32 + ln) * 8];
        f32x16 sv0 = __builtin_amdgcn_mfma_f32_32x32x16_f16(kf, qf0, m12, 0, 0, 0);
        f32x16 sv1 = __builtin_amdgcn_mfma_f32_32x32x16_f16(kf, qf1, m12, 0, 0, 0);
        float pe0[16], pe1[16];
#pragma unroll
        for (int r = 0; r < 16; r++) {
            pe0[r] = __builtin_amdgcn_exp2f(sv0[r]);
            pe1[r] = __builtin_amdgcn_exp2f(sv1[r]);
        }
#pragma unroll
        for (int ks = 0; ks < 2; ks++) {
            unsigned int a1 = bcu(cvt2h(pe0[8*ks+0], pe0[8*ks+1]));
            unsigned int a2 = bcu(cvt2h(pe0[8*ks+2], pe0[8*ks+3]));
            unsigned int a3 = bcu(cvt2h(pe0[8*ks+4], pe0[8*ks+5]));
            unsigned int a4 = bcu(cvt2h(pe0[8*ks+6], pe0[8*ks+7]));
            swap32(a1, a3, hi);
            swap32(a2, a4, hi);
            half8 pa0 = __builtin_bit_cast(half8, make_uint4(a1, a2, a3, a4));
            unsigned int b1 = bcu(cvt2h(pe1[8*ks+0], pe1[8*ks+1]));
            unsigned int b2 = bcu(cvt2h(pe1[8*ks+2], pe1[8*ks+3]));
            unsigned int b3 = bcu(cvt2h(pe1[8*ks+4], pe1[8*ks+5]));
            unsigned int b4 = bcu(cvt2h(pe1[8*ks+6], pe1[8*ks+7]));
            swap32(b1, b3, hi);
            swap32(b2, b4, hi);
            half8 pa1 = __builtin_bit_cast(half8, make_uint4(b1, b2, b3, b4));
            int chunk = t * 4 + ks * 2 + hi;
            half8 vf = hzero;
            if (ln <= 8) vf = *(const half8*)&VS[chunk * 72 + ln * 8];
            acc0 = __builtin_amdgcn_mfma_f32_32x32x16_f16(pa0, vf, acc0, 0, 0, 0);
            acc1 = __builtin_amdgcn_mfma_f32_32x32x16_f16(pa1, vf, acc1, 0, 0, 0);
        }
    }

#pragma unroll
    for (int sstep = 0; sstep < 2; sstep++) {
        int n0l = (wv + 4 * sstep) * 32;   // local row within this half's 256
        const f32x16& acc = sstep ? acc1 : acc0;
#pragma unroll
        for (int r = 0; r < 16; r++) {
            float av = acc[r];
            float den = __shfl(av, 8 + 32 * hi, 64);
            float ov = av * __builtin_amdgcn_rcpf(den);
            if (ln < 8) {
                int nrow = n0l + (r & 3) + 8 * (r >> 2) + 4 * hi;
                OL[nrow * 8 + ln] = (_Float16)ov;
            }
        }
    }
    __syncthreads();
    ((uint4*)(O + ((size_t)h * RTOT + row0 + half_ * 256) * 8))[tid] = ((const uint4*)OL)[tid];
}

// ---------------------------------------------------------------------------
// O-projection GEMM (R16-proven): 192 x 512; atomics into stats_o.
// ---------------------------------------------------------------------------
__global__ __launch_bounds__(512) void gemm_o(
        const _Float16* __restrict__ X,
        const float* __restrict__ Wo, const float* __restrict__ bo,
        _Float16* __restrict__ Yo, float* __restrict__ st) {
    __shared__ char WT[8192];
    __shared__ _Float16 YT[256 * 72];
    __shared__ float red[128];
    int tid = threadIdx.x;
#pragma unroll
    for (int j = 0; j < 8; j++) {
        int i = j * 512 + tid;
        int d = i >> 6, e = i & 63;
        int off = ((e * 64 + d) * 2) ^ ((e & 7) << 4);
        *(_Float16*)(&WT[off]) = (_Float16)Wo[i];
    }
    if (tid < 128) red[tid] = 0.f;

    int wvi = tid >> 6, lane = tid & 63, ln = lane & 31, hi = lane >> 5;
    int rowBase = blockIdx.x * 256 + wvi * 32;

    half8 af[4];
#pragma unroll
    for (int kc = 0; kc < 4; kc++)
        af[kc] = *(const half8*)(X + ((size_t)(2*kc + hi) * RTOT + rowBase + ln) * 8);
    __syncthreads();

    f32x16 acc[2];
#pragma unroll
    for (int ct = 0; ct < 2; ct++) {
#pragma unroll
        for (int r = 0; r < 16; r++) acc[ct][r] = 0.f;
        int e = ct * 32 + ln;
#pragma unroll
        for (int kc = 0; kc < 4; kc++) {
            half8 bf = ldbf(WT, e, kc * 16 + 8 * hi);
            acc[ct] = __builtin_amdgcn_mfma_f32_32x32x16_f16(af[kc], bf, acc[ct], 0, 0, 0);
        }
    }

#pragma unroll
    for (int ct = 0; ct < 2; ct++) {
        int cc = ct * 32 + ln;
        float bv_ = bo[cc];
        float s = 0.f, q = 0.f;
#pragma unroll
        for (int r = 0; r < 16; r++) {
            float v = acc[ct][r] + bv_;
            s += v; q += v * v;
            int lrow = wvi * 32 + (r & 3) + 8 * (r >> 2) + 4 * hi;
            YT[lrow * 72 + cc] = (_Float16)v;
        }
        s += __shfl_xor(s, 32, 64);
        q += __shfl_xor(q, 32, 64);
        if (lane < 32) {
            atomicAdd(&red[cc], s);
            atomicAdd(&red[64 + cc], q);
        }
    }
    __syncthreads();
    if (tid < 128) atomicAdd(&st[tid], red[tid]);

#pragma unroll
    for (int j = 0; j < 4; j++) {
        int idx = j * 512 + tid;
        int r = idx >> 3, c8 = idx & 7;
        half8 v = *(const half8*)&YT[r * 72 + c8 * 8];
        *(half8*)(Yo + ((size_t)(blockIdx.x * 256 + r) * 64 + c8 * 8)) = v;
    }
}

// ---------------------------------------------------------------------------
// BN-ReLU from raw stats (R16-proven): grid 1536 x 256.
// ---------------------------------------------------------------------------
__global__ __launch_bounds__(256) void norm_relu16(const _Float16* __restrict__ Y,
                                                   const float* __restrict__ st,
                                                   const float* __restrict__ g,
                                                   const float* __restrict__ be,
                                                   float* __restrict__ out) {
    __shared__ float CF[128];
    int tid = threadIdx.x;
    if (tid < 64) {
        float inv = 1.f / (float)RTOT;
        float mean = st[tid] * inv;
        float var  = st[64 + tid] * inv - mean * mean;
        float a = g[tid] * rsqrtf(var + EPSF);
        CF[tid] = a;
        CF[64 + tid] = be[tid] - mean * a;
    }
    __syncthreads();
    int i = blockIdx.x * 256 + tid;
    half8 y = ((const half8*)Y)[i];
    int cb = (i & 7) * 8;
    float4 o0, o1;
    o0.x = fmaxf(CF[cb+0]*(float)y[0] + CF[64+cb+0], 0.f);
    o0.y = fmaxf(CF[cb+1]*(float)y[1] + CF[64+cb+1], 0.f);
    o0.z = fmaxf(CF[cb+2]*(float)y[2] + CF[64+cb+2], 0.f);
    o0.w = fmaxf(CF[cb+3]*(float)y[3] + CF[64+cb+3], 0.f);
    o1.x = fmaxf(CF[cb+4]*(float)y[4] + CF[64+cb+4], 0.f);
    o1.y = fmaxf(CF[cb+5]*(float)y[5] + CF[64+cb+5], 0.f);
    o1.z = fmaxf(CF[cb+6]*(float)y[6] + CF[64+cb+6], 0.f);
    o1.w = fmaxf(CF[cb+7]*(float)y[7] + CF[64+cb+7], 0.f);
    ((float4*)out)[2*i]   = o0;
    ((float4*)out)[2*i+1] = o1;
}

extern "C" void kernel_launch(void* const* d_in, const int* in_sizes, int n_in,
                              void* d_out, int out_size, void* d_ws, size_t ws_size,
                              hipStream_t stream) {
    const float* Q    = (const float*)d_in[0];
    const float* Kin  = (const float*)d_in[1];
    const float* mask = (const float*)d_in[2];
    const float* Wq = (const float*)d_in[4];
    const float* bq = (const float*)d_in[5];
    const float* gq = (const float*)d_in[6];
    const float* betaq = (const float*)d_in[7];
    const float* Wk = (const float*)d_in[8];
    const float* bk = (const float*)d_in[9];
    const float* gk = (const float*)d_in[10];
    const float* betak = (const float*)d_in[11];
    const float* Wv = (const float*)d_in[12];
    const float* bv = (const float*)d_in[13];
    const float* gv = (const float*)d_in[14];
    const float* betav = (const float*)d_in[15];
    const float* Wo = (const float*)d_in[16];
    const float* bo = (const float*)d_in[17];
    const float* go = (const float*)d_in[18];
    const float* betao = (const float*)d_in[19];

    const size_t TSZ = (size_t)RTOT * 64;
    _Float16* Yq = (_Float16*)d_ws;
    _Float16* Yk = Yq + TSZ;
    _Float16* Vr = Yk + TSZ;                      // RTOT*72 halfs
    _Float16* Ob = Vr + (size_t)RTOT * 72;
    _Float16* Yo = Ob + TSZ;
    _Float16* zt = Yo + TSZ;                      // 8 * RTOT halfs
    float* sp1 = (float*)(zt + (size_t)8 * RTOT); // 3*192*128 floats
    float* stats_o = sp1 + 3 * 192 * 128;         // 128 floats

    dim3 gqkv(192, 3);
    gemm_qkv<<<gqkv, 512, 0, stream>>>(Q, Kin, mask, Wq, bq, Wk, bk, Wv, bv,
                                       Yq, Yk, Vr, zt, sp1, stats_o);

    attn_mfma<<<1536, 256, 0, stream>>>(Yq, Yk, Vr, zt, sp1,
                                        gq, betaq, gk, betak, gv, betav, Ob);

    gemm_o<<<192, 512, 0, stream>>>(Ob, Wo, bo, Yo, stats_o);

    norm_relu16<<<1536, 256, 0, stream>>>(Yo, stats_o, go, betao, (float*)d_out);
}

// Round 21
// 74.686 us; speedup vs baseline: 1.2086x; 1.2086x over previous
//
#include <hip/hip_runtime.h>
#include <hip/hip_bf16.h>

#define RTOT 49152
#define RT9  442368               // (RTOT/8) * 72, V-interleaved per-head stride
#define EPSF 1e-5f
#define SCQ 0.5101062398836783f   // (1/sqrt(8)) * log2(e)

typedef _Float16 h2 __attribute__((ext_vector_type(2)));
typedef _Float16 half8 __attribute__((ext_vector_type(8)));
typedef float f32x16 __attribute__((ext_vector_type(16)));

__device__ __forceinline__ h2 cvt2h(float a, float b) {
    return __builtin_bit_cast(h2, __builtin_amdgcn_cvt_pkrtz(a, b));
}
__device__ __forceinline__ unsigned int bcu(h2 v) { return __builtin_bit_cast(unsigned int, v); }

__device__ __forceinline__ void swap32(unsigned int& x, unsigned int& y, int hi) {
#if __has_builtin(__builtin_amdgcn_permlane32_swap)
    auto r = __builtin_amdgcn_permlane32_swap(x, y, false, false);
    x = r[0]; y = r[1];
#else
    unsigned int xs = (unsigned int)__shfl_xor((int)x, 32, 64);
    unsigned int ys = (unsigned int)__shfl_xor((int)y, 32, 64);
    unsigned int nx = hi ? ys : x;
    unsigned int ny = hi ? y : xs;
    x = nx; y = ny;
#endif
}

__device__ __forceinline__ half8 ldaf(const float* __restrict__ X, size_t base) {
    const float4* p = (const float4*)(X + base);
    float4 x = p[0], y = p[1];
    uint4 u = make_uint4(bcu(cvt2h(x.x, x.y)), bcu(cvt2h(x.z, x.w)),
                         bcu(cvt2h(y.x, y.y)), bcu(cvt2h(y.z, y.w)));
    return __builtin_bit_cast(half8, u);
}
__device__ __forceinline__ half8 ldbf(const char* WT, int e, int k0) {
    int off = ((e * 64 + k0) * 2) ^ ((e & 7) << 4);
    return *(const half8*)(WT + off);
}

// ---------------------------------------------------------------------------
// QKV projection (R19-proven): grid (192,3) x 512 thr, non-atomic stats
// partials sp1, block (0,0) zeroes stats_o. LDS-transpose coalesced stores.
// ---------------------------------------------------------------------------
__global__ __launch_bounds__(512) void gemm_qkv(
        const float* __restrict__ Qin, const float* __restrict__ Kin,
        const float* __restrict__ mask,
        const float* __restrict__ Wq, const float* __restrict__ bq,
        const float* __restrict__ Wk, const float* __restrict__ bk,
        const float* __restrict__ Wv, const float* __restrict__ bv,
        _Float16* __restrict__ Yq, _Float16* __restrict__ Yk,
        _Float16* __restrict__ Vr, _Float16* __restrict__ zt,
        float* __restrict__ sp1, float* __restrict__ stats_o) {
    __shared__ char WT[8192];
    __shared__ _Float16 YT[256 * 72];
    __shared__ float red[128];
    int tid = threadIdx.x;
    int which = blockIdx.y;
    const float* X    = which ? Kin : Qin;
    const float* W    = which == 0 ? Wq : (which == 1 ? Wk : Wv);
    const float* bias = which == 0 ? bq : (which == 1 ? bk : bv);

#pragma unroll
    for (int j = 0; j < 8; j++) {
        int i = j * 512 + tid;
        int d = i >> 6, e = i & 63;
        int off = ((e * 64 + d) * 2) ^ ((e & 7) << 4);
        *(_Float16*)(&WT[off]) = (_Float16)W[i];
    }
    if (tid < 128) red[tid] = 0.f;
    if (blockIdx.x == 0 && which == 0 && tid < 128)
        stats_o[tid] = 0.f;   // zero gemm_o's atomic slot (2 kernels downstream)

    int wvi = tid >> 6, lane = tid & 63, ln = lane & 31, hi = lane >> 5;
    int row = blockIdx.x * 256 + wvi * 32 + ln;

    half8 af[4];
#pragma unroll
    for (int kc = 0; kc < 4; kc++)
        af[kc] = ldaf(X, (size_t)row * 64 + kc * 16 + 8 * hi);

    if ((int)(blockIdx.x % 3) == which && tid < 256) {
        int mrow = blockIdx.x * 256 + tid;
        const float4* mr = (const float4*)(mask + (size_t)mrow * 64);
        float s[8];
#pragma unroll
        for (int h8 = 0; h8 < 8; h8++) s[h8] = 0.f;
#pragma unroll
        for (int i = 0; i < 16; i++) {
            float4 m = mr[i];
            s[i >> 1] += m.x + m.y + m.z + m.w;
        }
#pragma unroll
        for (int h8 = 0; h8 < 8; h8++)
            zt[(size_t)h8 * RTOT + mrow] = (_Float16)((s[h8] == 0.f) ? 0.f : SCQ);
    }
    __syncthreads();

    f32x16 acc[2];
#pragma unroll
    for (int ct = 0; ct < 2; ct++) {
#pragma unroll
        for (int r = 0; r < 16; r++) acc[ct][r] = 0.f;
        int e = ct * 32 + ln;
#pragma unroll
        for (int kc = 0; kc < 4; kc++) {
            half8 bf = ldbf(WT, e, kc * 16 + 8 * hi);
            acc[ct] = __builtin_amdgcn_mfma_f32_32x32x16_f16(af[kc], bf, acc[ct], 0, 0, 0);
        }
    }

#pragma unroll
    for (int ct = 0; ct < 2; ct++) {
        int cc = ct * 32 + ln;
        float bv_ = bias[cc];
        float s = 0.f, q = 0.f;
#pragma unroll
        for (int r = 0; r < 16; r++) {
            float v = acc[ct][r] + bv_;
            s += v; q += v * v;
            int lrow = wvi * 32 + (r & 3) + 8 * (r >> 2) + 4 * hi;
            YT[lrow * 72 + cc] = (_Float16)v;
        }
        s += __shfl_xor(s, 32, 64);
        q += __shfl_xor(q, 32, 64);
        if (lane < 32) {
            atomicAdd(&red[cc], s);
            atomicAdd(&red[64 + cc], q);
        }
    }
    __syncthreads();
    if (tid < 128)
        sp1[((size_t)which * 192 + blockIdx.x) * 128 + tid] = red[tid];

    if (which < 2) {
        _Float16* Y = which == 0 ? Yq : Yk;
#pragma unroll
        for (int j = 0; j < 4; j++) {
            int idx = j * 512 + tid;
            int h = idx >> 8, r = idx & 255;
            half8 v = *(const half8*)&YT[r * 72 + h * 8];
            *(half8*)(Y + ((size_t)h * RTOT + blockIdx.x * 256 + r) * 8) = v;
        }
    } else {
        int chBase = blockIdx.x * 32;
#pragma unroll
        for (int j = 0; j < 4; j++) {
            int idx = j * 512 + tid;
            int h = idx >> 8, rem = idx & 255;
            int ch = rem >> 3, c = rem & 7;
            half8 w;
#pragma unroll
            for (int i = 0; i < 8; i++)
                w[i] = YT[(ch * 8 + i) * 72 + h * 8 + c];
            *(half8*)(Vr + (size_t)h * RT9 + (size_t)(chBase + ch) * 72 + c * 8) = w;
        }
        if (tid < 256) {
            int h = tid >> 5, ch = tid & 31;
            half8 one8;
#pragma unroll
            for (int i = 0; i < 8; i++) one8[i] = (_Float16)1.0f;
            *(half8*)(Vr + (size_t)h * RT9 + (size_t)(chBase + ch) * 72 + 64) = one8;
        }
    }
}

// ---------------------------------------------------------------------------
// MFMA attention (R19-proven): 768 blocks x 512 thr, strip-fused t-loop.
// Prologue reduces sp1 partials for this head's 48 stat values, overlapped
// with the K/V/Q prefetch loads.
// ---------------------------------------------------------------------------
__global__ __launch_bounds__(512) void attn_mfma(
        const _Float16* __restrict__ Yq, const _Float16* __restrict__ Yk,
        const _Float16* __restrict__ Vr, const _Float16* __restrict__ zt,
        const float* __restrict__ sp1,
        const float* __restrict__ gq, const float* __restrict__ betaq,
        const float* __restrict__ gk, const float* __restrict__ betak,
        const float* __restrict__ gv, const float* __restrict__ betav,
        _Float16* __restrict__ O) {
    __shared__ __align__(16) _Float16 KL[4096];
    __shared__ __align__(16) _Float16 VS[4608];
    __shared__ __align__(16) _Float16 OL[4096];
    __shared__ float SR[48];    // raw sums: [s][i16]  (i16<8 sum, >=8 ssq)
    __shared__ float CF2[48];   // Q=0..15, K=16..31, V=32..47 ([a8|b8] each)

    int p = blockIdx.x;
    int h = p / 96;
    int bt = p - h * 96;
    int row0 = bt * 512;
    int co = h * 8;
    int tid = threadIdx.x;

    int wv = tid >> 6;
    int lane = tid & 63;
    int ln = lane & 31;
    int hi = lane >> 5;

    const _Float16* Ykh = Yk + ((size_t)h * RTOT + row0) * 8;
    const _Float16* Vrh = Vr + (size_t)h * RT9 + (size_t)(row0 >> 3) * 72;
    const _Float16* Yqh = Yq + ((size_t)h * RTOT + row0) * 8;

    // prefetch Q rows + mask factors + K row + V chunks (latency overlaps
    // with the stats reduction below)
    half8 yqs[2];
    float zms[2];
    if (!hi) {
#pragma unroll
        for (int s = 0; s < 2; s++) {
            int n0 = (wv + 8 * s) * 32;
            yqs[s] = *(const half8*)(Yqh + (n0 + ln) * 8);
            zms[s] = (float)zt[(size_t)h * RTOT + row0 + n0 + ln];
        }
    }
    half8 yk = *(const half8*)(Ykh + tid * 8);
    half8 vv0 = ((const half8*)Vrh)[tid];
    half8 vv1;
    if (tid < 64) vv1 = ((const half8*)Vrh)[512 + tid];

    // reduce per-block stat partials for this head's 48 values
    if (tid < 384) {
        int v = tid >> 3;          // 0..47
        int part = tid & 7;
        int s = v >> 4, i16 = v & 15;
        int ci = (i16 < 8) ? (co + i16) : (64 + co + (i16 - 8));
        const float* base = sp1 + ((size_t)s * 192 + part * 24) * 128 + ci;
        float a = 0.f;
#pragma unroll
        for (int b = 0; b < 24; b++)
            a += base[b * 128];
        a += __shfl_xor(a, 1, 64);
        a += __shfl_xor(a, 2, 64);
        a += __shfl_xor(a, 4, 64);
        if (part == 0) SR[v] = a;
    }
    __syncthreads();
    if (tid < 24) {
        int s = tid >> 3, c7 = tid & 7;
        const float* g  = s == 0 ? gq : (s == 1 ? gk : gv);
        const float* be = s == 0 ? betaq : (s == 1 ? betak : betav);
        float inv = 1.f / (float)RTOT;
        float mean = SR[s * 16 + c7] * inv;
        float var  = SR[s * 16 + 8 + c7] * inv - mean * mean;
        float a = g[co + c7] * rsqrtf(var + EPSF);
        CF2[s * 16 + c7] = a;
        CF2[s * 16 + 8 + c7] = be[co + c7] - mean * a;
    }
    __syncthreads();   // CF2 ready

    {
        half8 kv;
#pragma unroll
        for (int c = 0; c < 8; c++)
            kv[c] = (_Float16)fmaxf(CF2[16 + c] * (float)yk[c] + CF2[24 + c], 0.f);
        *(half8*)&KL[tid * 8] = kv;
    }
    {
        int c = tid % 9;
        if (c < 8) {
            float a = CF2[32 + c], b = CF2[40 + c];
#pragma unroll
            for (int e = 0; e < 8; e++)
                vv0[e] = (_Float16)fmaxf(a * (float)vv0[e] + b, 0.f);
        }
        ((half8*)VS)[tid] = vv0;
        if (tid < 64) {
            int c1 = (512 + tid) % 9;
            if (c1 < 8) {
                float a = CF2[32 + c1], b = CF2[40 + c1];
#pragma unroll
                for (int e = 0; e < 8; e++)
                    vv1[e] = (_Float16)fmaxf(a * (float)vv1[e] + b, 0.f);
            }
            ((half8*)VS)[512 + tid] = vv1;
        }
    }
    __syncthreads();

    f32x16 m12;
#pragma unroll
    for (int r = 0; r < 16; r++) m12[r] = -12.f;
    half8 hzero;
#pragma unroll
    for (int i = 0; i < 8; i++) hzero[i] = (_Float16)0.f;

    half8 qf0 = hzero, qf1 = hzero;
    if (!hi) {
#pragma unroll
        for (int c = 0; c < 8; c++) {
            qf0[c] = (_Float16)(fmaxf(CF2[c] * (float)yqs[0][c] + CF2[8 + c], 0.f) * zms[0]);
            qf1[c] = (_Float16)(fmaxf(CF2[c] * (float)yqs[1][c] + CF2[8 + c], 0.f) * zms[1]);
        }
    }

    f32x16 acc0, acc1;
#pragma unroll
    for (int r = 0; r < 16; r++) { acc0[r] = 0.f; acc1[r] = 0.f; }

#pragma unroll 2
    for (int t = 0; t < 16; t++) {
        half8 kf = hzero;
        if (!hi) kf = *(const half8*)&KL[(t * 32 + ln) * 8];
        f32x16 sv0 = __builtin_amdgcn_mfma_f32_32x32x16_f16(kf, qf0, m12, 0, 0, 0);
        f32x16 sv1 = __builtin_amdgcn_mfma_f32_32x32x16_f16(kf, qf1, m12, 0, 0, 0);
        float pe0[16], pe1[16];
#pragma unroll
        for (int r = 0; r < 16; r++) {
            pe0[r] = __builtin_amdgcn_exp2f(sv0[r]);
            pe1[r] = __builtin_amdgcn_exp2f(sv1[r]);
        }
#pragma unroll
        for (int ks = 0; ks < 2; ks++) {
            unsigned int a1 = bcu(cvt2h(pe0[8*ks+0], pe0[8*ks+1]));
            unsigned int a2 = bcu(cvt2h(pe0[8*ks+2], pe0[8*ks+3]));
            unsigned int a3 = bcu(cvt2h(pe0[8*ks+4], pe0[8*ks+5]));
            unsigned int a4 = bcu(cvt2h(pe0[8*ks+6], pe0[8*ks+7]));
            swap32(a1, a3, hi);
            swap32(a2, a4, hi);
            half8 pa0 = __builtin_bit_cast(half8, make_uint4(a1, a2, a3, a4));
            unsigned int b1 = bcu(cvt2h(pe1[8*ks+0], pe1[8*ks+1]));
            unsigned int b2 = bcu(cvt2h(pe1[8*ks+2], pe1[8*ks+3]));
            unsigned int b3 = bcu(cvt2h(pe1[8*ks+4], pe1[8*ks+5]));
            unsigned int b4 = bcu(cvt2h(pe1[8*ks+6], pe1[8*ks+7]));
            swap32(b1, b3, hi);
            swap32(b2, b4, hi);
            half8 pa1 = __builtin_bit_cast(half8, make_uint4(b1, b2, b3, b4));
            int chunk = t * 4 + ks * 2 + hi;
            half8 vf = hzero;
            if (ln <= 8) vf = *(const half8*)&VS[chunk * 72 + ln * 8];
            acc0 = __builtin_amdgcn_mfma_f32_32x32x16_f16(pa0, vf, acc0, 0, 0, 0);
            acc1 = __builtin_amdgcn_mfma_f32_32x32x16_f16(pa1, vf, acc1, 0, 0, 0);
        }
    }

#pragma unroll
    for (int sstep = 0; sstep < 2; sstep++) {
        int n0 = (wv + 8 * sstep) * 32;
        const f32x16& acc = sstep ? acc1 : acc0;
#pragma unroll
        for (int r = 0; r < 16; r++) {
            float av = acc[r];
            float den = __shfl(av, 8 + 32 * hi, 64);
            float ov = av * __builtin_amdgcn_rcpf(den);
            if (ln < 8) {
                int nrow = n0 + (r & 3) + 8 * (r >> 2) + 4 * hi;
                OL[nrow * 8 + ln] = (_Float16)ov;
            }
        }
    }
    __syncthreads();
    ((uint4*)(O + ((size_t)h * RTOT + row0) * 8))[tid] = ((const uint4*)OL)[tid];
}

// ---------------------------------------------------------------------------
// O-projection GEMM (R16-proven): 192 x 512; atomics into stats_o (zeroed
// upstream by gemm_qkv).
// ---------------------------------------------------------------------------
__global__ __launch_bounds__(512) void gemm_o(
        const _Float16* __restrict__ X,
        const float* __restrict__ Wo, const float* __restrict__ bo,
        _Float16* __restrict__ Yo, float* __restrict__ st) {
    __shared__ char WT[8192];
    __shared__ _Float16 YT[256 * 72];
    __shared__ float red[128];
    int tid = threadIdx.x;
#pragma unroll
    for (int j = 0; j < 8; j++) {
        int i = j * 512 + tid;
        int d = i >> 6, e = i & 63;
        int off = ((e * 64 + d) * 2) ^ ((e & 7) << 4);
        *(_Float16*)(&WT[off]) = (_Float16)Wo[i];
    }
    if (tid < 128) red[tid] = 0.f;

    int wvi = tid >> 6, lane = tid & 63, ln = lane & 31, hi = lane >> 5;
    int rowBase = blockIdx.x * 256 + wvi * 32;

    half8 af[4];
#pragma unroll
    for (int kc = 0; kc < 4; kc++)
        af[kc] = *(const half8*)(X + ((size_t)(2*kc + hi) * RTOT + rowBase + ln) * 8);
    __syncthreads();

    f32x16 acc[2];
#pragma unroll
    for (int ct = 0; ct < 2; ct++) {
#pragma unroll
        for (int r = 0; r < 16; r++) acc[ct][r] = 0.f;
        int e = ct * 32 + ln;
#pragma unroll
        for (int kc = 0; kc < 4; kc++) {
            half8 bf = ldbf(WT, e, kc * 16 + 8 * hi);
            acc[ct] = __builtin_amdgcn_mfma_f32_32x32x16_f16(af[kc], bf, acc[ct], 0, 0, 0);
        }
    }

#pragma unroll
    for (int ct = 0; ct < 2; ct++) {
        int cc = ct * 32 + ln;
        float bv_ = bo[cc];
        float s = 0.f, q = 0.f;
#pragma unroll
        for (int r = 0; r < 16; r++) {
            float v = acc[ct][r] + bv_;
            s += v; q += v * v;
            int lrow = wvi * 32 + (r & 3) + 8 * (r >> 2) + 4 * hi;
            YT[lrow * 72 + cc] = (_Float16)v;
        }
        s += __shfl_xor(s, 32, 64);
        q += __shfl_xor(q, 32, 64);
        if (lane < 32) {
            atomicAdd(&red[cc], s);
            atomicAdd(&red[64 + cc], q);
        }
    }
    __syncthreads();
    if (tid < 128) atomicAdd(&st[tid], red[tid]);

#pragma unroll
    for (int j = 0; j < 4; j++) {
        int idx = j * 512 + tid;
        int r = idx >> 3, c8 = idx & 7;
        half8 v = *(const half8*)&YT[r * 72 + c8 * 8];
        *(half8*)(Yo + ((size_t)(blockIdx.x * 256 + r) * 64 + c8 * 8)) = v;
    }
}

// ---------------------------------------------------------------------------
// BN-ReLU from raw stats (R16-proven): grid 1536 x 256.
// ---------------------------------------------------------------------------
__global__ __launch_bounds__(256) void norm_relu16(const _Float16* __restrict__ Y,
                                                   const float* __restrict__ st,
                                                   const float* __restrict__ g,
                                                   const float* __restrict__ be,
                                                   float* __restrict__ out) {
    __shared__ float CF[128];
    int tid = threadIdx.x;
    if (tid < 64) {
        float inv = 1.f / (float)RTOT;
        float mean = st[tid] * inv;
        float var  = st[64 + tid] * inv - mean * mean;
        float a = g[tid] * rsqrtf(var + EPSF);
        CF[tid] = a;
        CF[64 + tid] = be[tid] - mean * a;
    }
    __syncthreads();
    int i = blockIdx.x * 256 + tid;
    half8 y = ((const half8*)Y)[i];
    int cb = (i & 7) * 8;
    float4 o0, o1;
    o0.x = fmaxf(CF[cb+0]*(float)y[0] + CF[64+cb+0], 0.f);
    o0.y = fmaxf(CF[cb+1]*(float)y[1] + CF[64+cb+1], 0.f);
    o0.z = fmaxf(CF[cb+2]*(float)y[2] + CF[64+cb+2], 0.f);
    o0.w = fmaxf(CF[cb+3]*(float)y[3] + CF[64+cb+3], 0.f);
    o1.x = fmaxf(CF[cb+4]*(float)y[4] + CF[64+cb+4], 0.f);
    o1.y = fmaxf(CF[cb+5]*(float)y[5] + CF[64+cb+5], 0.f);
    o1.z = fmaxf(CF[cb+6]*(float)y[6] + CF[64+cb+6], 0.f);
    o1.w = fmaxf(CF[cb+7]*(float)y[7] + CF[64+cb+7], 0.f);
    ((float4*)out)[2*i]   = o0;
    ((float4*)out)[2*i+1] = o1;
}

extern "C" void kernel_launch(void* const* d_in, const int* in_sizes, int n_in,
                              void* d_out, int out_size, void* d_ws, size_t ws_size,
                              hipStream_t stream) {
    const float* Q    = (const float*)d_in[0];
    const float* Kin  = (const float*)d_in[1];
    const float* mask = (const float*)d_in[2];
    const float* Wq = (const float*)d_in[4];
    const float* bq = (const float*)d_in[5];
    const float* gq = (const float*)d_in[6];
    const float* betaq = (const float*)d_in[7];
    const float* Wk = (const float*)d_in[8];
    const float* bk = (const float*)d_in[9];
    const float* gk = (const float*)d_in[10];
    const float* betak = (const float*)d_in[11];
    const float* Wv = (const float*)d_in[12];
    const float* bv = (const float*)d_in[13];
    const float* gv = (const float*)d_in[14];
    const float* betav = (const float*)d_in[15];
    const float* Wo = (const float*)d_in[16];
    const float* bo = (const float*)d_in[17];
    const float* go = (const float*)d_in[18];
    const float* betao = (const float*)d_in[19];

    const size_t TSZ = (size_t)RTOT * 64;
    _Float16* Yq = (_Float16*)d_ws;
    _Float16* Yk = Yq + TSZ;
    _Float16* Vr = Yk + TSZ;                      // RTOT*72 halfs
    _Float16* Ob = Vr + (size_t)RTOT * 72;
    _Float16* Yo = Ob + TSZ;
    _Float16* zt = Yo + TSZ;                      // 8 * RTOT halfs
    float* sp1 = (float*)(zt + (size_t)8 * RTOT); // 3*192*128 floats
    float* stats_o = sp1 + 3 * 192 * 128;         // 128 floats

    dim3 gqkv(192, 3);
    gemm_qkv<<<gqkv, 512, 0, stream>>>(Q, Kin, mask, Wq, bq, Wk, bk, Wv, bv,
                                       Yq, Yk, Vr, zt, sp1, stats_o);

    attn_mfma<<<768, 512, 0, stream>>>(Yq, Yk, Vr, zt, sp1,
                                       gq, betaq, gk, betak, gv, betav, Ob);

    gemm_o<<<192, 512, 0, stream>>>(Ob, Wo, bo, Yo, stats_o);

    norm_relu16<<<1536, 256, 0, stream>>>(Yo, stats_o, go, betao, (float*)d_out);
}